// Round 21
// baseline (102.802 us; speedup 1.0000x reference)
//
#include <hip/hip_runtime.h>

#define Bb 8
#define Tt 512
#define Uu 128
#define U1 129
#define Vv 128

#define OUT_OFF 0                               // float2 OUT[b][t][u] linear
#define NGRP 80                                 // pair-groups (4 pairs = 8 diagonals each)
#define GRECROWF 4096                           // floats per group record (64 lanes x 64)
#define GRECBSZ ((size_t)NGRP * GRECROWF)       // per-batch floats
#define GREC_OFF ((size_t)Bb * Tt * U1 * 2)
#define GCOLSTR 1284                            // per-batch floats: float4 x 321 pairs
#define GCOL_OFF (GREC_OFF + (size_t)Bb * GRECBSZ)
#define RES_OFF (GCOL_OFF + (size_t)Bb * GCOLSTR)

#define K_LN2    0.6931471805599453f
#define K_INVLN2 1.4426950408889634f
#define SENT (-1.0e30f)                         // finite sentinel; exp2(-big)=0, no inf/NaN

__device__ __forceinline__ float fexp2(float x) {
    float r; asm("v_exp_f32 %0, %1" : "=v"(r) : "v"(x)); return r;
}
__device__ __forceinline__ float flog2(float x) {
    float r; asm("v_log_f32 %0, %1" : "=v"(r) : "v"(x)); return r;
}
__device__ __forceinline__ float fmax3(float x, float y, float z) {
    float r; asm("v_max3_f32 %0, %1, %2, %3" : "=v"(r) : "v"(x), "v"(y), "v"(z));
    return r;
}
__device__ __forceinline__ float lae2(float x, float y) {
    float dd = x - y;
    float nad = __builtin_bit_cast(float, __builtin_bit_cast(int, dd) | 0x80000000);
    return fmaxf(x, y) + flog2(1.0f + fexp2(nad));
}
__device__ __forceinline__ float lae3(float x, float y, float z) {
    float m = fmax3(x, y, z);
    return m + flog2(fexp2(x - m) + fexp2(y - m) + fexp2(z - m));
}

// Stage A: band-restricted streaming LSE (r15 structure, unchanged).
__global__ __launch_bounds__(256) void lse_kernel(
    const float* __restrict__ logits, const int* __restrict__ y,
    const int* __restrict__ logit_lens, const int* __restrict__ y_lens,
    float* __restrict__ ws)
{
    const int b = blockIdx.y;
    const int t = blockIdx.x;
    if (t >= logit_lens[b]) return;
    const int Ue = y_lens[b];

    float2* outv = (float2*)(ws + OUT_OFF);
    const int wid  = threadIdx.x >> 6;
    const int lane = threadIdx.x & 63;
    const int g    = lane >> 4;
    const int gl   = lane & 15;
    const unsigned rowbase = ((unsigned)b * Tt + t) * U1;
    const int yb = b * Uu;

    for (int u0 = wid * 8; u0 <= Ue; u0 += 32) {
        const int ua = u0 + g;
        const int ub = u0 + 4 + g;
        const int uca = ua > Ue ? Ue : ua;
        const int ucb = ub > Ue ? Ue : ub;
        const float* pa = logits + (size_t)(rowbase + uca) * Vv;
        const float* pb = logits + (size_t)(rowbase + ucb) * Vv;
        float4 a1 = *(const float4*)(pa + gl * 4);
        float4 a2 = *(const float4*)(pa + 64 + gl * 4);
        float4 b1 = *(const float4*)(pb + gl * 4);
        float4 b2 = *(const float4*)(pb + 64 + gl * 4);

        float sa = (fexp2(a1.x * K_INVLN2) + fexp2(a1.y * K_INVLN2))
                 + (fexp2(a1.z * K_INVLN2) + fexp2(a1.w * K_INVLN2))
                 + (fexp2(a2.x * K_INVLN2) + fexp2(a2.y * K_INVLN2))
                 + (fexp2(a2.z * K_INVLN2) + fexp2(a2.w * K_INVLN2));
        float sb = (fexp2(b1.x * K_INVLN2) + fexp2(b1.y * K_INVLN2))
                 + (fexp2(b1.z * K_INVLN2) + fexp2(b1.w * K_INVLN2))
                 + (fexp2(b2.x * K_INVLN2) + fexp2(b2.y * K_INVLN2))
                 + (fexp2(b2.z * K_INVLN2) + fexp2(b2.w * K_INVLN2));
        #pragma unroll
        for (int off = 8; off; off >>= 1) {
            sa += __shfl_xor(sa, off);
            sb += __shfl_xor(sb, off);
        }
        float lseA = flog2(sa);
        float lseB = flog2(sb);

        float emA = SENT, emB = SENT;
        if (uca < Uu) {
            int yv = y[yb + uca];
            int c = yv & 3;
            float4 cv = (yv & 64) ? a2 : a1;
            float cand = (c == 0) ? cv.x : (c == 1) ? cv.y : (c == 2) ? cv.z : cv.w;
            float ev = __shfl(cand, (lane & 48) | ((yv & 63) >> 2));
            emA = ev * K_INVLN2 - lseA;
        }
        if (ucb < Uu) {
            int yv = y[yb + ucb];
            int c = yv & 3;
            float4 cv = (yv & 64) ? b2 : b1;
            float cand = (c == 0) ? cv.x : (c == 1) ? cv.y : (c == 2) ? cv.z : cv.w;
            float ev = __shfl(cand, (lane & 48) | ((yv & 63) >> 2));
            emB = ev * K_INVLN2 - lseB;
        }
        if (gl == 0) {
            if (ua <= Ue) outv[rowbase + ua] = make_float2(a1.x * K_INVLN2 - lseA, emA);
            if (ub <= Ue) outv[rowbase + ub] = make_float2(b1.x * K_INVLN2 - lseB, emB);
        }
    }
}

// Stage B: per-(batch, group of 4 pairs) coefficient builder + halo packing.
// D rows 8(g-1)..8g-1 from OUT -> pair coeffs A/B/C (r12-verified formulas) for
// pairs k=1..4 -> per-lane 64-float records holding exactly the slots each
// step updates: step1 j=2..9 (A8,B8,C8 @0,8,16), step2 j=4..9 (@24,30,36),
// step3 j=6..9 (@42,46,50), step4 j=8..9 (@54,56,58); slot s=2l-8+j, s<0=SENT.
// u=128 coeffs per pair -> GCOL[b][m] float4 {A,B,C,0}.
__global__ __launch_bounds__(256) void gcond_kernel(
    const int* __restrict__ logit_lens, const int* __restrict__ y_lens,
    float* __restrict__ ws)
{
    const int b = blockIdx.x / NGRP;
    const int g = blockIdx.x - b * NGRP + 1;            // 1..80
    const int np = (logit_lens[b] - 1 + y_lens[b]) >> 1;
    if (4 * (g - 1) >= np) return;
    const float2* outv = (const float2*)(ws + OUT_OFF);

    __shared__ float2 Dr[8][U1];
    __shared__ float ABC[3 * 4 * 136];                  // As|Bs|Cs x 4 pairs x idx(2l+j)
    __shared__ float recS[GRECROWF / NGRP * NGRP / 64];  // placeholder avoided below
    __shared__ float rec[4096];

    const int tid = threadIdx.x;
    for (int i = tid; i < 8 * U1; i += 256) {
        int row = i / U1, j = i - row * U1;
        int r = 8 * (g - 1) + row;
        int t = r - j;
        Dr[row][j] = (t >= 0 && t < Tt) ? outv[((size_t)b * Tt + t) * U1 + j]
                                        : make_float2(SENT, SENT);
    }
    __syncthreads();

    if (tid < 136) {
        const int s = tid - 8;
        #pragma unroll
        for (int k = 0; k < 4; ++k) {
            float A = SENT, B = SENT, C = SENT;
            if (s >= 0) {
                float2 d1 = Dr[2 * k][s], d2 = Dr[2 * k + 1][s];
                float2 d1m = (s >= 1) ? Dr[2 * k][s - 1] : make_float2(SENT, SENT);
                float d2my  = (s >= 1) ? Dr[2 * k + 1][s - 1].y : SENT;
                float d1m2y = (s >= 2) ? Dr[2 * k][s - 2].y : SENT;
                A = d1.x + d2.x;
                B = lae2(d1m.y + d2.x, d1m.x + d2my);
                C = d1m2y + d2my;
            }
            ABC[k * 136 + tid]        = A;
            ABC[544 + k * 136 + tid]  = B;
            ABC[1088 + k * 136 + tid] = C;
        }
    } else if (tid >= 160 && tid < 164) {
        const int k = tid - 160;
        float2 d1 = Dr[2 * k][128], d2 = Dr[2 * k + 1][128];
        float2 d1m = Dr[2 * k][127];
        float d2my  = Dr[2 * k + 1][127].y;
        float d1m2y = Dr[2 * k][126].y;
        float A = d1.x + d2.x;
        float B = lae2(d1m.y + d2.x, d1m.x + d2my);
        float C = d1m2y + d2my;
        ((float4*)(ws + GCOL_OFF))[(size_t)b * (GCOLSTR / 4) + 4 * (g - 1) + k + 1]
            = make_float4(A, B, C, 0.0f);
    }
    __syncthreads();

    if (tid < 64) {
        const int l = tid, i2 = 2 * l, base = l * 64;
        const int offA[4] = {0, 24, 42, 54}, offB[4] = {8, 30, 46, 56},
                  offC[4] = {16, 36, 50, 58}, jlo[4] = {2, 4, 6, 8};
        #pragma unroll
        for (int k = 0; k < 4; ++k) {
            const float* As = ABC + k * 136;
            const float* Bs = ABC + 544 + k * 136;
            const float* Cs = ABC + 1088 + k * 136;
            for (int j = jlo[k]; j <= 9; ++j) {
                rec[base + offA[k] + j - jlo[k]] = As[i2 + j];
                rec[base + offB[k] + j - jlo[k]] = Bs[i2 + j];
                rec[base + offC[k] + j - jlo[k]] = Cs[i2 + j];
            }
        }
        rec[base + 60] = 0.0f; rec[base + 61] = 0.0f;
        rec[base + 62] = 0.0f; rec[base + 63] = 0.0f;
    }
    __syncthreads();

    // transpose-copy: global layout float4 index ((g-1)*16 + q)*64 + lane
    float4* out4 = (float4*)(ws + GREC_OFF) + (size_t)b * (GRECBSZ / 4)
                 + (size_t)(g - 1) * 1024;
    const float4* rec4 = (const float4*)rec;
    for (int i = tid; i < 1024; i += 256) {
        int q = i >> 6, l = i & 63;
        out4[i] = rec4[l * 16 + q];
    }
}

// DP with halo replication: lane l keeps w[0..9] = alpha[2l-8 .. 2l+1].
// Pair-steps are pure in-lane VALU (no cross-lane on the chain); one batch of
// 8 independent shfls per 4 pair-steps (8 diagonals) refills the halo.
// u=128 lives in lane 63 (in-lane via own w9/w8 + GCOL coeffs).
template<bool H128>
__device__ __forceinline__ void dp_body(int b, int lane, int Tb, int Ub,
                                        float* __restrict__ ws)
{
    const float2* outv = (const float2*)(ws + OUT_OFF);
    const float4* GREC4 = (const float4*)(ws + GREC_OFF) + (size_t)b * (GRECBSZ / 4);
    const float4* GCOL4 = (const float4*)(ws + GCOL_OFF) + (size_t)b * (GCOLSTR / 4);
    int zv; asm volatile("v_mov_b32 %0, 0" : "=v"(zv));

    const int dend = Tb - 1 + Ub;          // [319,639]
    const int np   = dend >> 1;            // pairs
    const int ng   = np >> 2;              // full groups (>=39)
    const int lv   = np & 3;               // leftover pair steps
    const int rem  = dend & 1;             // final single step
    const int gmax = (np + 3) >> 2;        // groups incl. partial

    // init window: slot s=2l-8+j -> 0 at s==0 else SENT
    float w0,w1,w2,w3,w4,w5,w6,w7,w8,w9;
    {
        int s0 = 2 * lane - 8;
        w0=(s0==0)?0.0f:SENT;   w1=(s0+1==0)?0.0f:SENT;
        w2=(s0+2==0)?0.0f:SENT; w3=(s0+3==0)?0.0f:SENT;
        w4=(s0+4==0)?0.0f:SENT; w5=(s0+5==0)?0.0f:SENT;
        w6=(s0+6==0)?0.0f:SENT; w7=(s0+7==0)?0.0f:SENT;
        w8=(s0+8==0)?0.0f:SENT; w9=(s0+9==0)?0.0f:SENT;
    }
    float w128 = SENT;

    // tail/final loads up-front
    float2 F1 = make_float2(0,0), F2 = make_float2(0,0), G = make_float2(0,0);
    if (rem) {
        const int r = dend - 1;
        int j1 = 2 * lane, j2 = 2 * lane + 1;
        int t1 = r - j1; t1 = t1 > Tt - 1 ? Tt - 1 : t1;
        int t2 = r - j2; t2 = t2 > Tt - 1 ? Tt - 1 : t2;
        F1 = outv[((size_t)b * Tt + t1) * U1 + j1];
        F2 = outv[((size_t)b * Tt + t2) * U1 + j2];
        if constexpr (H128) G = outv[((size_t)b * Tt + (r - 128)) * U1 + 128];
    }
    float pbf = outv[((size_t)b * Tt + (Tb - 1)) * U1 + Ub + zv].x;

    float4 QA[16], QB[16], CLA[4], CLB[4];

#define LOADG(Q, CL, gg) { \
    const float4* P = GREC4 + (size_t)((gg) - 1) * 1024 + lane; \
    _Pragma("unroll") \
    for (int q = 0; q < 16; ++q) Q[q] = P[q * 64]; \
    if constexpr (H128) { \
        int m0 = 4 * ((gg) - 1) + 1 + zv; \
        CL[0] = GCOL4[m0]; CL[1] = GCOL4[m0 + 1]; \
        CL[2] = GCOL4[m0 + 2]; CL[3] = GCOL4[m0 + 3]; } }

#define PINQ(Q, CL) { \
    asm volatile("" : "+v"(Q[0].x),  "+v"(Q[1].x),  "+v"(Q[2].x),  "+v"(Q[3].x), \
                      "+v"(Q[4].x),  "+v"(Q[5].x),  "+v"(Q[6].x),  "+v"(Q[7].x)); \
    asm volatile("" : "+v"(Q[8].x),  "+v"(Q[9].x),  "+v"(Q[10].x), "+v"(Q[11].x), \
                      "+v"(Q[12].x), "+v"(Q[13].x), "+v"(Q[14].x), "+v"(Q[15].x)); \
    if constexpr (H128) \
        asm volatile("" : "+v"(CL[0].x), "+v"(CL[1].x), "+v"(CL[2].x), "+v"(CL[3].x)); }

#define STEP1(Q, CL) { float nw = SENT; \
    if constexpr (H128) nw = lae3(w128 + CL[0].x, w9 + CL[0].y, w8 + CL[0].z); \
    w9 = lae3(w9 + Q[1].w, w8 + Q[3].w, w7 + Q[5].w); \
    w8 = lae3(w8 + Q[1].z, w7 + Q[3].z, w6 + Q[5].z); \
    w7 = lae3(w7 + Q[1].y, w6 + Q[3].y, w5 + Q[5].y); \
    w6 = lae3(w6 + Q[1].x, w5 + Q[3].x, w4 + Q[5].x); \
    w5 = lae3(w5 + Q[0].w, w4 + Q[2].w, w3 + Q[4].w); \
    w4 = lae3(w4 + Q[0].z, w3 + Q[2].z, w2 + Q[4].z); \
    w3 = lae3(w3 + Q[0].y, w2 + Q[2].y, w1 + Q[4].y); \
    w2 = lae3(w2 + Q[0].x, w1 + Q[2].x, w0 + Q[4].x); \
    if constexpr (H128) w128 = nw; }

#define STEP2(Q, CL) { float nw = SENT; \
    if constexpr (H128) nw = lae3(w128 + CL[1].x, w9 + CL[1].y, w8 + CL[1].z); \
    w9 = lae3(w9 + Q[7].y, w8 + Q[8].w, w7 + Q[10].y); \
    w8 = lae3(w8 + Q[7].x, w7 + Q[8].z, w6 + Q[10].x); \
    w7 = lae3(w7 + Q[6].w, w6 + Q[8].y, w5 + Q[9].w); \
    w6 = lae3(w6 + Q[6].z, w5 + Q[8].x, w4 + Q[9].z); \
    w5 = lae3(w5 + Q[6].y, w4 + Q[7].w, w3 + Q[9].y); \
    w4 = lae3(w4 + Q[6].x, w3 + Q[7].z, w2 + Q[9].x); \
    if constexpr (H128) w128 = nw; }

#define STEP3(Q, CL) { float nw = SENT; \
    if constexpr (H128) nw = lae3(w128 + CL[2].x, w9 + CL[2].y, w8 + CL[2].z); \
    w9 = lae3(w9 + Q[11].y, w8 + Q[12].y, w7 + Q[13].y); \
    w8 = lae3(w8 + Q[11].x, w7 + Q[12].x, w6 + Q[13].x); \
    w7 = lae3(w7 + Q[10].w, w6 + Q[11].w, w5 + Q[12].w); \
    w6 = lae3(w6 + Q[10].z, w5 + Q[11].z, w4 + Q[12].z); \
    if constexpr (H128) w128 = nw; }

#define STEP4(Q, CL) { float nw = SENT; \
    if constexpr (H128) nw = lae3(w128 + CL[3].x, w9 + CL[3].y, w8 + CL[3].z); \
    w9 = lae3(w9 + Q[13].w, w8 + Q[14].y, w7 + Q[14].w); \
    w8 = lae3(w8 + Q[13].z, w7 + Q[14].x, w6 + Q[14].z); \
    if constexpr (H128) w128 = nw; }

#define EXCHG() { \
    float n0 = __shfl(w8, lane - 4), n1 = __shfl(w9, lane - 4); \
    float n2 = __shfl(w8, lane - 3), n3 = __shfl(w9, lane - 3); \
    float n4 = __shfl(w8, lane - 2), n5 = __shfl(w9, lane - 2); \
    float n6 = __shfl(w8, lane - 1), n7 = __shfl(w9, lane - 1); \
    int l2 = 2 * lane; \
    w0 = (l2 < 8) ? SENT : n0;     w1 = (l2 + 1 < 8) ? SENT : n1; \
    w2 = (l2 + 2 < 8) ? SENT : n2; w3 = (l2 + 3 < 8) ? SENT : n3; \
    w4 = (l2 + 4 < 8) ? SENT : n4; w5 = (l2 + 5 < 8) ? SENT : n5; \
    w6 = (l2 + 6 < 8) ? SENT : n6; w7 = (l2 + 7 < 8) ? SENT : n7; }

#define GROUPX(Q, CL) { STEP1(Q, CL) STEP2(Q, CL) STEP3(Q, CL) STEP4(Q, CL) EXCHG() }

    LOADG(QA, CLA, 1)
    LOADG(QB, CLB, (2 > gmax ? gmax : 2))

    int g = 1;
    for (; g + 1 <= ng; g += 2) {
        PINQ(QA, CLA) GROUPX(QA, CLA)
        { int dn = g + 2 > gmax ? gmax : g + 2; LOADG(QA, CLA, dn) }
        PINQ(QB, CLB) GROUPX(QB, CLB)
        { int dn = g + 3 > gmax ? gmax : g + 3; LOADG(QB, CLB, dn) }
    }
    if (g <= ng) { PINQ(QA, CLA) GROUPX(QA, CLA) }

    if (lv) {                      // leftover pair steps from partial group gmax
        LOADG(QA, CLA, gmax)
        PINQ(QA, CLA)
        STEP1(QA, CLA)
        if (lv >= 2) STEP2(QA, CLA)
        if (lv >= 3) STEP3(QA, CLA)
    }

    if (rem) {                     // final single step diag dend-1 -> dend
        float aL  = __shfl(w9, lane - 1);        // alpha[2l-1]
        float emL = __shfl(F2.y, lane - 1);      // em(slot 2l-1)
        float nw = SENT;
        if constexpr (H128)
            nw = lae2(w128 + G.x, w9 + F2.y);    // lane63: alpha[127]=w9, em(127)=own F2.y
        float nx = lae2(w8 + F1.x, (lane == 0) ? SENT : aL + emL);
        float ny = lae2(w9 + F2.x, w8 + F1.y);
        w8 = nx; w9 = ny;
        if constexpr (H128) w128 = nw;
    }

    float a;
    if constexpr (H128) {
        a = __shfl(w128, 63);
    } else {
        float ax = __shfl(w8, Ub >> 1);
        float ay = __shfl(w9, Ub >> 1);
        a = (Ub & 1) ? ay : ax;
    }
    if (lane == 0) {
        ws[RES_OFF + b] = -(a + pbf) * K_LN2;
    }
#undef LOADG
#undef PINQ
#undef STEP1
#undef STEP2
#undef STEP3
#undef STEP4
#undef EXCHG
#undef GROUPX
}

__global__ __launch_bounds__(64) void dp_kernel(
    const int* __restrict__ logit_lens, const int* __restrict__ y_lens,
    float* __restrict__ ws)
{
    const int b = blockIdx.x;
    const int lane = threadIdx.x;
    const int Tb = logit_lens[b];
    const int Ub = y_lens[b];
    if (Ub == 128) dp_body<true>(b, lane, Tb, Ub, ws);
    else           dp_body<false>(b, lane, Tb, Ub, ws);
}

__global__ void mean_kernel(const float* __restrict__ res, float* __restrict__ out)
{
    if (threadIdx.x == 0) {
        float s = 0.0f;
        #pragma unroll
        for (int i = 0; i < Bb; ++i) s += res[i];
        out[0] = s * (1.0f / Bb);
    }
}

extern "C" void kernel_launch(void* const* d_in, const int* in_sizes, int n_in,
                              void* d_out, int out_size, void* d_ws, size_t ws_size,
                              hipStream_t stream) {
    const float* logits     = (const float*)d_in[0];
    const int*   y          = (const int*)d_in[1];
    const int*   logit_lens = (const int*)d_in[2];
    const int*   y_lens     = (const int*)d_in[3];
    float* ws  = (float*)d_ws;
    float* out = (float*)d_out;

    dim3 lgrid(Tt, Bb);
    lse_kernel<<<lgrid, 256, 0, stream>>>(logits, y, logit_lens, y_lens, ws);
    gcond_kernel<<<Bb * NGRP, 256, 0, stream>>>(logit_lens, y_lens, ws);
    dp_kernel<<<Bb, 64, 0, stream>>>(logit_lens, y_lens, ws);
    mean_kernel<<<1, 64, 0, stream>>>(ws + RES_OFF, out);
}

// Round 22
// 68.988 us; speedup vs baseline: 1.4901x; 1.4901x over previous
//
#include <hip/hip_runtime.h>

#define Bb 8
#define Tt 512
#define Uu 128
#define U1 129
#define Vv 128

#define OUT_OFF 0                          // float2 OUT[b][t][u] linear
#define CTROWS 321                         // pair rows m = 0..320 (1..320 used)
#define PCKROW 512                         // floats per packed pair row (64 lanes x 8)
#define PCKBSZ ((size_t)CTROWS * PCKROW)
#define PCK_OFF ((size_t)Bb * Tt * U1 * 2)
#define CTCOL_OFF (PCK_OFF + (size_t)Bb * PCKBSZ)      // float4 {A,B,C,0}[b][m] (u=128)
// k=4 condensed tables: W row q covers diags 4q-4 -> 4q
#define WROWF 768                          // 64 lanes x 12 floats (10 used)
#define WROWS 160                          // q = 0..159 (1..159 used)
#define WBSZ ((size_t)WROWS * WROWF)
#define W_OFF (CTCOL_OFF + (size_t)Bb * CTROWS * 4)
#define WCOL_OFF (W_OFF + (size_t)Bb * WBSZ)           // 8 floats per (b,q): u=128 coeffs
#define RES_OFF (WCOL_OFF + (size_t)Bb * WROWS * 8)

#define K_LN2    0.6931471805599453f
#define K_INVLN2 1.4426950408889634f
#define SENT (-1.0e30f)                    // finite sentinel; exp2(-big)=0, no inf/NaN

__device__ __forceinline__ float fexp2(float x) {
    float r; asm("v_exp_f32 %0, %1" : "=v"(r) : "v"(x)); return r;
}
__device__ __forceinline__ float flog2(float x) {
    float r; asm("v_log_f32 %0, %1" : "=v"(r) : "v"(x)); return r;
}
__device__ __forceinline__ float fmax3(float x, float y, float z) {
    float r; asm("v_max3_f32 %0, %1, %2, %3" : "=v"(r) : "v"(x), "v"(y), "v"(z));
    return r;
}

// Stage A: band-restricted streaming LSE (r15 structure, unchanged).
__global__ __launch_bounds__(256) void lse_kernel(
    const float* __restrict__ logits, const int* __restrict__ y,
    const int* __restrict__ logit_lens, const int* __restrict__ y_lens,
    float* __restrict__ ws)
{
    const int b = blockIdx.y;
    const int t = blockIdx.x;
    if (t >= logit_lens[b]) return;
    const int Ue = y_lens[b];

    float2* outv = (float2*)(ws + OUT_OFF);
    const int wid  = threadIdx.x >> 6;
    const int lane = threadIdx.x & 63;
    const int g    = lane >> 4;
    const int gl   = lane & 15;
    const unsigned rowbase = ((unsigned)b * Tt + t) * U1;
    const int yb = b * Uu;

    for (int u0 = wid * 8; u0 <= Ue; u0 += 32) {
        const int ua = u0 + g;
        const int ub = u0 + 4 + g;
        const int uca = ua > Ue ? Ue : ua;
        const int ucb = ub > Ue ? Ue : ub;
        const float* pa = logits + (size_t)(rowbase + uca) * Vv;
        const float* pb = logits + (size_t)(rowbase + ucb) * Vv;
        float4 a1 = *(const float4*)(pa + gl * 4);
        float4 a2 = *(const float4*)(pa + 64 + gl * 4);
        float4 b1 = *(const float4*)(pb + gl * 4);
        float4 b2 = *(const float4*)(pb + 64 + gl * 4);

        float sa = (fexp2(a1.x * K_INVLN2) + fexp2(a1.y * K_INVLN2))
                 + (fexp2(a1.z * K_INVLN2) + fexp2(a1.w * K_INVLN2))
                 + (fexp2(a2.x * K_INVLN2) + fexp2(a2.y * K_INVLN2))
                 + (fexp2(a2.z * K_INVLN2) + fexp2(a2.w * K_INVLN2));
        float sb = (fexp2(b1.x * K_INVLN2) + fexp2(b1.y * K_INVLN2))
                 + (fexp2(b1.z * K_INVLN2) + fexp2(b1.w * K_INVLN2))
                 + (fexp2(b2.x * K_INVLN2) + fexp2(b2.y * K_INVLN2))
                 + (fexp2(b2.z * K_INVLN2) + fexp2(b2.w * K_INVLN2));
        #pragma unroll
        for (int off = 8; off; off >>= 1) {
            sa += __shfl_xor(sa, off);
            sb += __shfl_xor(sb, off);
        }
        float lseA = flog2(sa);
        float lseB = flog2(sb);

        float emA = SENT, emB = SENT;
        if (uca < Uu) {
            int yv = y[yb + uca];
            int c = yv & 3;
            float4 cv = (yv & 64) ? a2 : a1;
            float cand = (c == 0) ? cv.x : (c == 1) ? cv.y : (c == 2) ? cv.z : cv.w;
            float ev = __shfl(cand, (lane & 48) | ((yv & 63) >> 2));
            emA = ev * K_INVLN2 - lseA;
        }
        if (ucb < Uu) {
            int yv = y[yb + ucb];
            int c = yv & 3;
            float4 cv = (yv & 64) ? b2 : b1;
            float cand = (c == 0) ? cv.x : (c == 1) ? cv.y : (c == 2) ? cv.z : cv.w;
            float ev = __shfl(cand, (lane & 48) | ((yv & 63) >> 2));
            emB = ev * K_INVLN2 - lseB;
        }
        if (gl == 0) {
            if (ua <= Ue) outv[rowbase + ua] = make_float2(a1.x * K_INVLN2 - lseA, emA);
            if (ub <= Ue) outv[rowbase + ub] = make_float2(b1.x * K_INVLN2 - lseB, emB);
        }
    }
}

__device__ __forceinline__ float lae2(float x, float y) {
    float dd = x - y;
    float nad = __builtin_bit_cast(float, __builtin_bit_cast(int, dd) | 0x80000000);
    return fmaxf(x, y) + flog2(1.0f + fexp2(nad));
}
__device__ __forceinline__ float lae3(float x, float y, float z) {
    float m = fmax3(x, y, z);
    return m + flog2(fexp2(x - m) + fexp2(y - m) + fexp2(z - m));
}
__device__ __forceinline__ float lae5(float a, float b, float c, float d, float e) {
    float m = fmax3(a, b, c);
    m = fmax3(m, d, e);
    return m + flog2(fexp2(a - m) + fexp2(b - m) + fexp2(c - m)
                   + fexp2(d - m) + fexp2(e - m));
}

// Stage B: pair-condensation coefficients, PACKED (r15 structure, unchanged).
__global__ __launch_bounds__(256) void cond_kernel(
    const int* __restrict__ logit_lens, const int* __restrict__ y_lens,
    float* __restrict__ ws)
{
    const int b = blockIdx.x / 320;
    const int m = blockIdx.x - b * 320 + 1;
    if (m > ((logit_lens[b] - 1 + y_lens[b]) >> 1)) return;
    const int r1 = 2 * m - 2, r2 = 2 * m - 1;
    const float2* outv = (const float2*)(ws + OUT_OFF);

    __shared__ float2 D1[U1], D2[U1];
    __shared__ float pckS[PCKROW];
    for (int q = threadIdx.x; q < 2 * U1; q += 256) {
        const int which = q >= U1;
        const int j = q - which * U1;
        const int t = (which ? r2 : r1) - j;
        float2 val = make_float2(SENT, SENT);
        if (t >= 0 && t < Tt) val = outv[((size_t)b * Tt + t) * U1 + j];
        (which ? D2 : D1)[j] = val;
    }
    __syncthreads();

    const int u = threadIdx.x;
    if (u <= 128) {
        float2 d1  = D1[u], d2 = D2[u];
        float2 d1m = (u >= 1) ? D1[u - 1] : make_float2(SENT, SENT);
        float d2my  = (u >= 1) ? D2[u - 1].y : SENT;
        float d1m2y = (u >= 2) ? D1[u - 2].y : SENT;
        float A = d1.x + d2.x;
        float B = lae2(d1m.y + d2.x, d1m.x + d2my);
        float C = d1m2y + d2my;
        if (u < 128) {
            int base = (u >> 1) * 8 + (u & 1);
            pckS[base]     = A;
            pckS[base + 2] = B;
            pckS[base + 4] = C;
            if ((u & 1) == 0) { pckS[base + 6] = 0.0f; pckS[base + 7] = 0.0f; }
        } else {
            ((float4*)(ws + CTCOL_OFF))[(size_t)b * CTROWS + m] = make_float4(A, B, C, 0.0f);
        }
    }
    __syncthreads();

    float* pckG = ws + PCK_OFF + (size_t)b * PCKBSZ + (size_t)m * PCKROW;
    for (int i = threadIdx.x; i < PCKROW; i += 256) pckG[i] = pckS[i];
}

// Stage C: k=4 condensation. Compose pair-matrices m1=2q-1 (applied first) and
// m2=2q: banded 3-diag x 3-diag -> 5-diag in the (add, lae) semiring:
//   W0[u]=A2+A1[u]; W1=lae2(A2+B1[u], B2+A1[u-1]);
//   W2=lae3(A2+C1[u], B2+B1[u-1], C2+A1[u-2]);
//   W3=lae2(B2+C1[u-1], C2+B1[u-2]); W4=C2+C1[u-2].
// SENT pads at u<0 keep dead arms dead. W row q: per-lane 12 floats
// {W0e,W0o,W1e,W1o | W2e,W2o,W3e,W3o | W4e,W4o,pad,pad}; u=128 -> WCOL[b][q][8].
__global__ __launch_bounds__(256) void compose_kernel(
    const int* __restrict__ logit_lens, const int* __restrict__ y_lens,
    float* __restrict__ ws)
{
    const int b = blockIdx.x / 159;
    const int q = blockIdx.x - b * 159 + 1;        // 1..159
    const int dend = logit_lens[b] - 1 + y_lens[b];
    if (4 * q > dend) return;
    const int m1 = 2 * q - 1, m2 = 2 * q;
    const float* PCKb = ws + PCK_OFF + (size_t)b * PCKBSZ;
    const float4* COLb = (const float4*)(ws + CTCOL_OFF) + (size_t)b * CTROWS;

    __shared__ float a1s[131], b1s[131], c1s[131];  // index u+2, [0..1]=SENT pad
    __shared__ float wrk[WROWF];
    const int u = threadIdx.x;
    if (u < 2) { a1s[u] = SENT; b1s[u] = SENT; c1s[u] = SENT; }
    if (u < 128) {
        const float* p = PCKb + (size_t)m1 * PCKROW + (u >> 1) * 8;
        int par = u & 1;
        a1s[u + 2] = p[par]; b1s[u + 2] = p[2 + par]; c1s[u + 2] = p[4 + par];
    } else if (u == 128) {
        float4 cc = COLb[m1];
        a1s[130] = cc.x; b1s[130] = cc.y; c1s[130] = cc.z;
    }
    __syncthreads();

    if (u <= 128) {
        float A2, B2, C2;
        if (u < 128) {
            const float* p = PCKb + (size_t)m2 * PCKROW + (u >> 1) * 8;
            int par = u & 1;
            A2 = p[par]; B2 = p[2 + par]; C2 = p[4 + par];
        } else {
            float4 cc = COLb[m2];
            A2 = cc.x; B2 = cc.y; C2 = cc.z;
        }
        float A1 = a1s[u + 2], A1m = a1s[u + 1], A1m2 = a1s[u];
        float B1 = b1s[u + 2], B1m = b1s[u + 1], B1m2 = b1s[u];
        float C1 = c1s[u + 2], C1m = c1s[u + 1], C1m2 = c1s[u];
        float W0 = A2 + A1;
        float W1 = lae2(A2 + B1, B2 + A1m);
        float W2 = lae3(A2 + C1, B2 + B1m, C2 + A1m2);
        float W3 = lae2(B2 + C1m, C2 + B1m2);
        float W4 = C2 + C1m2;
        if (u < 128) {
            int base = (u >> 1) * 12 + (u & 1);
            wrk[base]     = W0;
            wrk[base + 2] = W1;
            wrk[base + 4] = W2;
            wrk[base + 6] = W3;
            wrk[base + 8] = W4;
            if ((u & 1) == 0) { wrk[base + 10] = 0.0f; wrk[base + 11] = 0.0f; }
        } else {
            float* wc = ws + WCOL_OFF + ((size_t)b * WROWS + q) * 8;
            wc[0] = W0; wc[1] = W1; wc[2] = W2; wc[3] = W3; wc[4] = W4;
            wc[5] = 0.0f; wc[6] = 0.0f; wc[7] = 0.0f;
        }
    }
    __syncthreads();

    float* wg = ws + W_OFF + (size_t)b * WBSZ + (size_t)q * WROWF;
    for (int i = threadIdx.x; i < WROWF; i += 256) wg[i] = wrk[i];
}

// rotate lane i <- lane i-1 (mod 64). MODE 0/1: DPP (runtime-verified), 2: shuffle.
template<int MODE>
__device__ __forceinline__ float rot1(float x, int lane) {
    if constexpr (MODE == 2) {
        float s = __shfl_up(x, 1);
        float w = __shfl(x, 63);
        return (lane == 0) ? w : s;
    } else {
        constexpr int CTRL = (MODE == 0) ? 0x13C : 0x134;
        int i = __builtin_bit_cast(int, x);
        i = __builtin_amdgcn_update_dpp(i, i, CTRL, 0xF, 0xF, true);
        return __builtin_bit_cast(float, i);
    }
}

// DP over k=4 condensed diagonals: <=159 serial iterations, then a pair-step
// and/or single-step tail (r12/r15-verified paths). Ring 8 (80 VGPR -> no spill).
template<int MODE, bool H128>
__device__ __forceinline__ void dp_body(int b, int lane, int Tb, int Ub,
                                        float* __restrict__ ws)
{
    const float2* outv = (const float2*)(ws + OUT_OFF);
    const float* PCKb = ws + PCK_OFF + (size_t)b * PCKBSZ;
    const float4* COLb = (const float4*)(ws + CTCOL_OFF) + (size_t)b * CTROWS;
    const float* WTb = ws + W_OFF + (size_t)b * WBSZ;
    const float* WCb = ws + WCOL_OFF + (size_t)b * WROWS * 8;
    int zv; asm volatile("v_mov_b32 %0, 0" : "=v"(zv));  // opaque 0: force VMEM

    float px = (lane == 0) ? 0.0f : SENT;
    float py = SENT, p2 = SENT;
    const int dend = Tb - 1 + Ub;      // in [319, 639]
    const int nq   = dend >> 2;        // k=4 iterations (79..159)
    const int rem  = dend & 3;

    // tail loads issued up-front (retired long before use)
    const int mpair = 2 * nq + 1;      // pair row covering 4nq -> 4nq+2 (always in-bounds)
    float4 Qp = *(const float4*)(PCKb + (size_t)mpair * PCKROW + (lane << 3));
    float2 Rp = *(const float2*)(PCKb + (size_t)mpair * PCKROW + (lane << 3) + 4);
    float4 Op = make_float4(SENT, SENT, SENT, 0.0f);
    if constexpr (H128) Op = COLb[mpair + zv];

    float2 F1 = make_float2(0,0), F2 = make_float2(0,0), G = make_float2(0,0);
    if (rem & 1) {
        const int r = dend - 1;
        int j1 = 2 * lane, j2 = 2 * lane + 1;
        int t1 = r - j1; t1 = t1 > Tt - 1 ? Tt - 1 : t1;   // clamp: out-of-lattice only
        int t2 = r - j2; t2 = t2 > Tt - 1 ? Tt - 1 : t2;
        F1 = outv[((size_t)b * Tt + t1) * U1 + j1];
        F2 = outv[((size_t)b * Tt + t2) * U1 + j2];
        if constexpr (H128) G = outv[((size_t)b * Tt + (r - 128)) * U1 + 128];
    }
    float pbf = outv[((size_t)b * Tt + (Tb - 1)) * U1 + Ub + zv].x;

    float4 A0,A1,A2,A3,A4,A5,A6,A7;    // {W0e,W0o,W1e,W1o}
    float4 B0,B1,B2,B3,B4,B5,B6,B7;    // {W2e,W2o,W3e,W3o}
    float2 C0,C1,C2,C3,C4,C5,C6,C7;    // {W4e,W4o}
    float4 Oa0,Oa1,Oa2,Oa3,Oa4,Oa5,Oa6,Oa7;  // u=128: {W0,W1,W2,W3}
    float2 Oc0,Oc1,Oc2,Oc3,Oc4,Oc5,Oc6,Oc7;  // u=128: {W4,pad}

#define LOADW(i, qq) { unsigned o = (unsigned)(qq) * WROWF + lane * 12; \
    A##i = *(const float4*)(WTb + o); \
    B##i = *(const float4*)(WTb + o + 4); \
    C##i = *(const float2*)(WTb + o + 8); \
    if constexpr (H128) { \
        Oa##i = *(const float4*)(WCb + (qq) * 8 + zv); \
        Oc##i = *(const float2*)(WCb + (qq) * 8 + 4 + zv); } }

#define PIN(i) if constexpr (H128) { \
        asm volatile("" : "+v"(A##i.x), "+v"(A##i.y), "+v"(A##i.z), "+v"(A##i.w), \
                          "+v"(B##i.x), "+v"(B##i.y), "+v"(B##i.z), "+v"(B##i.w), \
                          "+v"(C##i.x), "+v"(C##i.y), \
                          "+v"(Oa##i.x), "+v"(Oa##i.y), "+v"(Oa##i.z), "+v"(Oa##i.w), \
                          "+v"(Oc##i.x)); \
    } else { \
        asm volatile("" : "+v"(A##i.x), "+v"(A##i.y), "+v"(A##i.z), "+v"(A##i.w), \
                          "+v"(B##i.x), "+v"(B##i.y), "+v"(B##i.z), "+v"(B##i.w), \
                          "+v"(C##i.x), "+v"(C##i.y)); \
    }

    // even u=2l: alpha[u-1..u-4] = p1y, p1x, p2y, p2x; odd u=2l+1: px, p1y, p1x, p2y
#define COMP4(i) { \
    float p1y = rot1<MODE>(py, lane); \
    float p1x = rot1<MODE>(px, lane); \
    float p2y = rot1<MODE>(p1y, lane); \
    float p2x = rot1<MODE>(p1x, lane); \
    float nx = lae5(px + A##i.x, p1y + A##i.z, p1x + B##i.x, p2y + B##i.z, p2x + C##i.x); \
    float ny = lae5(py + A##i.y, px + A##i.w, p1y + B##i.y, p1x + B##i.w, p2y + C##i.y); \
    if constexpr (H128) p2 = lae5(p2 + Oa##i.x, p1y + Oa##i.y, p1x + Oa##i.z, \
                                  p2y + Oa##i.w, p2x + Oc##i.x); \
    px = nx; py = ny; }

    LOADW(0,1) LOADW(1,2) LOADW(2,3) LOADW(3,4)
    LOADW(4,5) LOADW(5,6) LOADW(6,7) LOADW(7,8)

    int q = 1;
    for (; q + 7 <= nq; q += 8) {
        PIN(0) COMP4(0) { int dn = q + 8  > nq ? nq : q + 8;  LOADW(0, dn) }
        PIN(1) COMP4(1) { int dn = q + 9  > nq ? nq : q + 9;  LOADW(1, dn) }
        PIN(2) COMP4(2) { int dn = q + 10 > nq ? nq : q + 10; LOADW(2, dn) }
        PIN(3) COMP4(3) { int dn = q + 11 > nq ? nq : q + 11; LOADW(3, dn) }
        PIN(4) COMP4(4) { int dn = q + 12 > nq ? nq : q + 12; LOADW(4, dn) }
        PIN(5) COMP4(5) { int dn = q + 13 > nq ? nq : q + 13; LOADW(5, dn) }
        PIN(6) COMP4(6) { int dn = q + 14 > nq ? nq : q + 14; LOADW(6, dn) }
        PIN(7) COMP4(7) { int dn = q + 15 > nq ? nq : q + 15; LOADW(7, dn) }
    }
#define TAILW(i) if (q <= nq) { PIN(i) COMP4(i) q++; }
    TAILW(0) TAILW(1) TAILW(2) TAILW(3) TAILW(4) TAILW(5) TAILW(6)

    if (rem >= 2) {   // pair step: diag 4nq -> 4nq+2
        float pm1 = rot1<MODE>(py, lane);
        float pm0 = rot1<MODE>(px, lane);
        float nx = lae3(px + Qp.x, pm1 + Qp.z, pm0 + Rp.x);
        float ny = lae3(py + Qp.y, px + Qp.w, pm1 + Rp.y);
        if constexpr (H128) p2 = lae3(p2 + Op.x, pm1 + Op.y, pm0 + Op.z);
        px = nx; py = ny;
    }
    if (rem & 1) {    // single step: diag dend-1 -> dend, operands from OUT
        float pm  = rot1<MODE>(py, lane);
        float pmE = rot1<MODE>(F2.y, lane);
        float pmE0 = (lane == 0) ? SENT : pmE;
        float nx = lae2(px + F1.x, pm + pmE0);
        float ny = lae2(py + F2.x, px + F1.y);
        if constexpr (H128) p2 = lae2(p2 + G.x, pm + pmE);
        px = nx; py = ny;
    }

    float a;
    if constexpr (H128) {
        a = __shfl(p2, 0);
    } else {
        float ax = __shfl(px, Ub >> 1);
        float ay = __shfl(py, Ub >> 1);
        a = (Ub & 1) ? ay : ax;
    }
    if (lane == 0) {
        ws[RES_OFF + b] = -(a + pbf) * K_LN2;
    }
#undef LOADW
#undef PIN
#undef COMP4
#undef TAILW
}

__global__ __launch_bounds__(64) void dp_kernel(
    const int* __restrict__ logit_lens, const int* __restrict__ y_lens,
    float* __restrict__ ws)
{
    const int b = blockIdx.x;
    const int lane = threadIdx.x;
    const int Tb = logit_lens[b];
    const int Ub = y_lens[b];
    const bool h = (Ub == 128);
    int li = lane;
    int r0 = __builtin_amdgcn_update_dpp(li, li, 0x13C /*WAVE_ROR1*/, 0xF, 0xF, true);
    int r1 = __builtin_amdgcn_update_dpp(li, li, 0x134 /*WAVE_ROL1*/, 0xF, 0xF, true);
    int want = (lane + 63) & 63;
    if (__all(r0 == want)) {
        if (h) dp_body<0, true>(b, lane, Tb, Ub, ws);
        else   dp_body<0, false>(b, lane, Tb, Ub, ws);
    } else if (__all(r1 == want)) {
        if (h) dp_body<1, true>(b, lane, Tb, Ub, ws);
        else   dp_body<1, false>(b, lane, Tb, Ub, ws);
    } else {
        if (h) dp_body<2, true>(b, lane, Tb, Ub, ws);
        else   dp_body<2, false>(b, lane, Tb, Ub, ws);
    }
}

__global__ void mean_kernel(const float* __restrict__ res, float* __restrict__ out)
{
    if (threadIdx.x == 0) {
        float s = 0.0f;
        #pragma unroll
        for (int i = 0; i < Bb; ++i) s += res[i];
        out[0] = s * (1.0f / Bb);
    }
}

extern "C" void kernel_launch(void* const* d_in, const int* in_sizes, int n_in,
                              void* d_out, int out_size, void* d_ws, size_t ws_size,
                              hipStream_t stream) {
    const float* logits     = (const float*)d_in[0];
    const int*   y          = (const int*)d_in[1];
    const int*   logit_lens = (const int*)d_in[2];
    const int*   y_lens     = (const int*)d_in[3];
    float* ws  = (float*)d_ws;
    float* out = (float*)d_out;

    dim3 lgrid(Tt, Bb);
    lse_kernel<<<lgrid, 256, 0, stream>>>(logits, y, logit_lens, y_lens, ws);
    cond_kernel<<<Bb * 320, 256, 0, stream>>>(logit_lens, y_lens, ws);
    compose_kernel<<<Bb * 159, 256, 0, stream>>>(logit_lens, y_lens, ws);
    dp_kernel<<<Bb, 64, 0, stream>>>(logit_lens, y_lens, ws);
    mean_kernel<<<1, 64, 0, stream>>>(ws + RES_OFF, out);
}